// Round 1
// baseline (264.030 us; speedup 1.0000x reference)
//
#include <hip/hip_runtime.h>
#include <hip/hip_bf16.h>

typedef __bf16 bf16_t;
typedef __bf16 bf16x8 __attribute__((ext_vector_type(8)));
typedef __bf16 bf16x4 __attribute__((ext_vector_type(4)));
typedef float f32x4 __attribute__((ext_vector_type(4)));

__device__ __forceinline__ bf16_t f2bf(float f) {
    __hip_bfloat16 h = __float2bfloat16(f);   // RNE
    return __builtin_bit_cast(bf16_t, h);
}

// async global->LDS, 16B per lane, dest = wave-uniform base + lane*16
#define GLD16(g, l)                                                        \
    __builtin_amdgcn_global_load_lds(                                      \
        (const __attribute__((address_space(1))) void*)(g),                \
        (__attribute__((address_space(3))) void*)(l), 16, 0, 0)

// ---------------------------------------------------------------------------
// Convert WR_w (256x512 f32) -> bf16
__global__ void __launch_bounds__(256) cvt_kernel(const float* __restrict__ src,
                                                  bf16_t* __restrict__ dst) {
    int i = blockIdx.x * 256 + threadIdx.x;   // 32768 threads, 4 elems each
    float4 v = ((const float4*)src)[i];
    bf16x4 o;
    o[0] = f2bf(v.x); o[1] = f2bf(v.y); o[2] = f2bf(v.z); o[3] = f2bf(v.w);
    ((bf16x4*)dst)[i] = o;
}

// ---------------------------------------------------------------------------
// Embedding gather: e0[row,:] = bf16(table[tokens[row],:]) ; row in [0,131072)
__global__ void __launch_bounds__(256) gather_kernel(const int* __restrict__ tokens,
                                                     const float* __restrict__ table,
                                                     bf16_t* __restrict__ e0) {
    int tid = threadIdx.x;
    int lane = tid & 63;
    int w = tid >> 6;
    long row = (long)blockIdx.x * 4 + w;        // wave-uniform
    int tok = tokens[row];                      // scalar load per wave
    const float4* src = (const float4*)(table + (long)tok * 256);
    float4 v = src[lane];                       // 16B per lane, 64 lanes = row
    bf16x4 o;
    o[0] = f2bf(v.x); o[1] = f2bf(v.y); o[2] = f2bf(v.z); o[3] = f2bf(v.w);
    *(bf16x4*)(e0 + row * 256 + lane * 4) = o;
}

// ---------------------------------------------------------------------------
// One tree level: out[m,n] = tanh( sum_k A[m,k]*W[n,k] + bias[n] )
// A: Mout x 512 bf16 (prev level viewed as pairs), W: 256x512 bf16, out: Mout x 256 bf16
// Tile 128x128, BK=32, 4 waves in 2x2, each wave 64x64 (4x4 frags of 16x16x32 MFMA)
__global__ void __launch_bounds__(256) level_gemm(const bf16_t* __restrict__ A,
                                                  const bf16_t* __restrict__ W,
                                                  const float* __restrict__ bias,
                                                  bf16_t* __restrict__ out) {
    constexpr int K = 512, N = 256, BM = 128, BK = 32;
    __shared__ __align__(16) bf16_t As[BM * BK];
    __shared__ __align__(16) bf16_t Bs[BM * BK];

    const int tid = threadIdx.x;
    const int lane = tid & 63;
    const int w = tid >> 6;
    const int wm = w >> 1, wn = w & 1;
    const long brow = (long)blockIdx.x * BM;
    const int bcol = blockIdx.y * BM;           // 0 or 128
    const int lr = lane & 15;
    const int lk = (lane >> 4) << 3;

    // staging addresses: issue i covers bytes (i*4+w)*1024 + lane*16 of the tile
    const int oe0 = (w << 9) + lane * 8;        // elem offset, i=0
    const int oe1 = oe0 + 2048;                 // i=1
    const int r0 = oe0 >> 5, k0 = oe0 & 31;
    const int r1 = oe1 >> 5, k1 = oe1 & 31;
    const bf16_t* gA0 = A + (brow + r0) * K + k0;
    const bf16_t* gA1 = A + (brow + r1) * K + k1;
    const bf16_t* gB0 = W + (long)(bcol + r0) * K + k0;
    const bf16_t* gB1 = W + (long)(bcol + r1) * K + k1;
    char* lA0 = (char*)As + (w << 10);
    char* lA1 = (char*)As + ((4 + w) << 10);
    char* lB0 = (char*)Bs + (w << 10);
    char* lB1 = (char*)Bs + ((4 + w) << 10);

    f32x4 acc[4][4];
    const f32x4 zero = {0.f, 0.f, 0.f, 0.f};
#pragma unroll
    for (int i = 0; i < 4; ++i)
#pragma unroll
        for (int j = 0; j < 4; ++j) acc[i][j] = zero;

    for (int kt = 0; kt < K; kt += BK) {
        GLD16(gA0 + kt, lA0);
        GLD16(gA1 + kt, lA1);
        GLD16(gB0 + kt, lB0);
        GLD16(gB1 + kt, lB1);
        __syncthreads();   // drains vmcnt: tile ready

        bf16x8 af[4], bfr[4];
#pragma unroll
        for (int mt = 0; mt < 4; ++mt)
            af[mt] = *(const bf16x8*)&As[(((wm << 6) + (mt << 4) + lr) << 5) + lk];
#pragma unroll
        for (int nt = 0; nt < 4; ++nt)
            bfr[nt] = *(const bf16x8*)&Bs[(((wn << 6) + (nt << 4) + lr) << 5) + lk];
#pragma unroll
        for (int mt = 0; mt < 4; ++mt)
#pragma unroll
            for (int nt = 0; nt < 4; ++nt)
                acc[mt][nt] = __builtin_amdgcn_mfma_f32_16x16x32_bf16(
                    af[mt], bfr[nt], acc[mt][nt], 0, 0, 0);
        __syncthreads();   // all reads done before next stage overwrites
    }

    // epilogue: bias + tanh, store bf16. C/D map: col=lane&15, row=(lane>>4)*4+r
    const int crow = (lane >> 4) << 2;
#pragma unroll
    for (int nt = 0; nt < 4; ++nt) {
        int col = bcol + (wn << 6) + (nt << 4) + lr;
        float bv = bias[col];
#pragma unroll
        for (int mt = 0; mt < 4; ++mt) {
            long row0 = brow + (wm << 6) + (mt << 4) + crow;
#pragma unroll
            for (int r = 0; r < 4; ++r) {
                float s = acc[mt][nt][r] + bv;
                float e2x = __expf(2.0f * s);
                float t = 1.0f - 2.0f * __builtin_amdgcn_rcpf(e2x + 1.0f);
                out[(row0 + r) * N + col] = f2bf(t);
            }
        }
    }
}

// ---------------------------------------------------------------------------
// Head: hidden = relu(root @ WF^T + bF); out = hidden @ WO^T + bO
// one block per batch row
__global__ void __launch_bounds__(256) head_kernel(const bf16_t* __restrict__ root,
                                                   const float* __restrict__ WFw,
                                                   const float* __restrict__ WFb,
                                                   const float* __restrict__ WOw,
                                                   const float* __restrict__ WOb,
                                                   float* __restrict__ out) {
    __shared__ float r[256];
    __shared__ float h[256];
    int b = blockIdx.x, tid = threadIdx.x;
    r[tid] = (float)root[(long)b * 256 + tid];
    __syncthreads();

    float s = WFb[tid];
    const float4* wrow = (const float4*)(WFw + (long)tid * 256);
#pragma unroll 8
    for (int d4 = 0; d4 < 64; ++d4) {
        float4 wv = wrow[d4];
        int d = d4 * 4;
        s += r[d] * wv.x + r[d + 1] * wv.y + r[d + 2] * wv.z + r[d + 3] * wv.w;
    }
    h[tid] = fmaxf(s, 0.0f);
    __syncthreads();

    if (tid < 64) {
#pragma unroll
        for (int c = 0; c < 5; ++c) {
            const float* wo = WOw + c * 256;
            float p = h[tid] * wo[tid] + h[tid + 64] * wo[tid + 64] +
                      h[tid + 128] * wo[tid + 128] + h[tid + 192] * wo[tid + 192];
#pragma unroll
            for (int off = 32; off > 0; off >>= 1) p += __shfl_down(p, off);
            if (tid == 0) out[b * 5 + c] = p + WOb[c];
        }
    }
}

// ---------------------------------------------------------------------------
extern "C" void kernel_launch(void* const* d_in, const int* in_sizes, int n_in,
                              void* d_out, int out_size, void* d_ws, size_t ws_size,
                              hipStream_t stream) {
    const int*   tokens = (const int*)d_in[0];
    const float* table  = (const float*)d_in[1];
    const float* WRw    = (const float*)d_in[2];
    const float* WRb    = (const float*)d_in[3];
    const float* WFw    = (const float*)d_in[4];
    const float* WFb    = (const float*)d_in[5];
    const float* WOw    = (const float*)d_in[6];
    const float* WOb    = (const float*)d_in[7];
    float* out = (float*)d_out;

    char* ws = (char*)d_ws;
    bf16_t* bufA = (bf16_t*)ws;                              // 131072*256 bf16 = 64 MiB
    bf16_t* bufB = (bf16_t*)(ws + (size_t)67108864);         // 65536*256 bf16 = 32 MiB
    bf16_t* Wbf  = (bf16_t*)(ws + (size_t)100663296);        // 131072 bf16 = 256 KiB

    cvt_kernel<<<128, 256, 0, stream>>>(WRw, Wbf);
    gather_kernel<<<32768, 256, 0, stream>>>(tokens, table, bufA);

    bf16_t* src = bufA;
    bf16_t* dst = bufB;
    for (int Mo = 65536; Mo >= 256; Mo >>= 1) {   // 9 levels
        level_gemm<<<dim3(Mo / 128, 2), 256, 0, stream>>>(src, Wbf, WRb, dst);
        bf16_t* t = src; src = dst; dst = t;
    }

    head_kernel<<<256, 256, 0, stream>>>(src, WFw, WFb, WOw, WOb, out);
}

// Round 2
// 211.488 us; speedup vs baseline: 1.2484x; 1.2484x over previous
//
#include <hip/hip_runtime.h>
#include <hip/hip_bf16.h>

typedef __bf16 bf16_t;
typedef __bf16 bf16x8 __attribute__((ext_vector_type(8)));
typedef __bf16 bf16x4 __attribute__((ext_vector_type(4)));
typedef float f32x4 __attribute__((ext_vector_type(4)));

__device__ __forceinline__ bf16_t f2bf(float f) {
    __hip_bfloat16 h = __float2bfloat16(f);   // RNE
    return __builtin_bit_cast(bf16_t, h);
}

__device__ __forceinline__ float tanh_fast(float s) {
    float e2x = __expf(2.0f * s);
    return 1.0f - 2.0f * __builtin_amdgcn_rcpf(e2x + 1.0f);
}

// async global->LDS, 16B per lane, LDS dest = wave-uniform base + lane*16,
// global src is per-lane.
#define GLD16(g, l)                                                        \
    __builtin_amdgcn_global_load_lds(                                      \
        (const __attribute__((address_space(1))) void*)(g),                \
        (__attribute__((address_space(3))) void*)(l), 16, 0, 0)

#define WAIT0_BAR() asm volatile("s_waitcnt vmcnt(0)\ns_barrier" ::: "memory")

// ---------------------------------------------------------------------------
// flat f32 -> bf16 convert, 4 elems/thread, grid covers exactly n/1024 blocks
__global__ void __launch_bounds__(256) cvt_kernel(const float* __restrict__ src,
                                                  bf16_t* __restrict__ dst) {
    int i = blockIdx.x * 256 + threadIdx.x;
    float4 v = ((const float4*)src)[i];
    bf16x4 o;
    o[0] = f2bf(v.x); o[1] = f2bf(v.y); o[2] = f2bf(v.z); o[3] = f2bf(v.w);
    ((bf16x4*)dst)[i] = o;
}

// ---------------------------------------------------------------------------
// One tree level: out[m,n] = tanh( sum_k A[m,k]*W[n,k] + bias[n] )
// GATHER=true: A rows come straight from the bf16 embed table via tokens
// (level 1); A[m, 0:256]=table[tok[2m]], A[m,256:512]=table[tok[2m+1]].
// Tile 128x128, BK=32, 2-phase double-buffered, 1 barrier per K-step.
template <bool GATHER>
__global__ void __launch_bounds__(256) level_gemm(const bf16_t* __restrict__ A,
                                                  const int* __restrict__ tokens,
                                                  const bf16_t* __restrict__ tableBf,
                                                  const bf16_t* __restrict__ W,
                                                  const float* __restrict__ bias,
                                                  bf16_t* __restrict__ out) {
    constexpr int K = 512, N = 256;
    __shared__ __align__(16) bf16_t As[2][4096];   // 128x32 per buf
    __shared__ __align__(16) bf16_t Bs[2][4096];

    const int tid = threadIdx.x;
    const int lane = tid & 63;
    const int w = tid >> 6;
    const int wm = w >> 1, wn = w & 1;
    const long brow = (long)blockIdx.x * 128;
    const int bcol = blockIdx.y * 128;
    const int lr = lane & 15;
    const int lk = (lane >> 4) << 3;

    // staging: issue i of wave w covers tile bytes [w*1024 + i*4096 + lane*16)
    const int r0 = (w << 4) + (lane >> 2);     // tile row, issue 0 (0..63)
    const int colE = (lane & 3) << 3;          // tile col elem (0,8,16,24)

    const bf16_t *paLo0, *paHi0, *paLo1, *paHi1, *pa0, *pa1;
    if constexpr (GATHER) {
        long m0 = brow + r0, m1 = m0 + 64;
        int t0a = tokens[2 * m0], t0b = tokens[2 * m0 + 1];
        int t1a = tokens[2 * m1], t1b = tokens[2 * m1 + 1];
        paLo0 = tableBf + (long)t0a * 256 + colE;
        paHi0 = tableBf + (long)t0b * 256 + colE;
        paLo1 = tableBf + (long)t1a * 256 + colE;
        paHi1 = tableBf + (long)t1b * 256 + colE;
    } else {
        pa0 = A + (brow + r0) * K + colE;
        pa1 = A + (brow + r0 + 64) * K + colE;
    }
    const bf16_t* pw0 = W + (long)(bcol + r0) * K + colE;
    const bf16_t* pw1 = pw0 + 64 * K;
    char* ldsA = (char*)&As[0][0] + (w << 10);
    char* ldsB = (char*)&Bs[0][0] + (w << 10);

    auto stage = [&](int buf, int kt) {
        const bf16_t *s0, *s1;
        if constexpr (GATHER) {
            int klo = kt & 255;
            bool lo = kt < 256;
            s0 = (lo ? paLo0 : paHi0) + klo;
            s1 = (lo ? paLo1 : paHi1) + klo;
        } else {
            s0 = pa0 + kt;
            s1 = pa1 + kt;
        }
        GLD16(s0, ldsA + (buf << 13));
        GLD16(s1, ldsA + (buf << 13) + 4096);
        GLD16(pw0 + kt, ldsB + (buf << 13));
        GLD16(pw1 + kt, ldsB + (buf << 13) + 4096);
    };

    f32x4 acc[4][4];
    const f32x4 zero = {0.f, 0.f, 0.f, 0.f};
#pragma unroll
    for (int i = 0; i < 4; ++i)
#pragma unroll
        for (int j = 0; j < 4; ++j) acc[i][j] = zero;

    stage(0, 0);
    WAIT0_BAR();
    for (int t = 0; t < 16; ++t) {
        const int cur = t & 1;
        if (t < 15) stage(cur ^ 1, (t + 1) << 5);   // prefetch next K-tile

        bf16x8 af[4], bfr[4];
#pragma unroll
        for (int mt = 0; mt < 4; ++mt)
            af[mt] = *(const bf16x8*)&As[cur][(((wm << 6) + (mt << 4) + lr) << 5) + lk];
#pragma unroll
        for (int nt = 0; nt < 4; ++nt)
            bfr[nt] = *(const bf16x8*)&Bs[cur][(((wn << 6) + (nt << 4) + lr) << 5) + lk];
#pragma unroll
        for (int mt = 0; mt < 4; ++mt)
#pragma unroll
            for (int nt = 0; nt < 4; ++nt)
                acc[mt][nt] = __builtin_amdgcn_mfma_f32_16x16x32_bf16(
                    af[mt], bfr[nt], acc[mt][nt], 0, 0, 0);

        if (t < 15) WAIT0_BAR();   // next tile landed; all waves' reads done
    }

    // epilogue: bias + tanh, store bf16. C/D map: col=lane&15, row=(lane>>4)*4+r
    const int crow = (lane >> 4) << 2;
#pragma unroll
    for (int nt = 0; nt < 4; ++nt) {
        int col = bcol + (wn << 6) + (nt << 4) + lr;
        float bv = bias[col];
#pragma unroll
        for (int mt = 0; mt < 4; ++mt) {
            long row0 = brow + (wm << 6) + (mt << 4) + crow;
#pragma unroll
            for (int r = 0; r < 4; ++r)
                out[(row0 + r) * N + col] = f2bf(tanh_fast(acc[mt][nt][r] + bv));
        }
    }
}

// ---------------------------------------------------------------------------
// Tail: one block owns a 128-row chunk of the 4096-row buffer and walks its
// own subtree: 64 -> 32 -> 16 -> 8 rows, then the head for its 8 batch rows.
// Per level: M = NM*16, N=256 (4 waves x 64 cols), K=512, BK=32, dbuf staging.
template <int NM, bool AG>
__device__ __forceinline__ void tail_level(const bf16_t* __restrict__ Ag,
                                           const bf16_t* __restrict__ Alds,
                                           const bf16_t* __restrict__ W,
                                           const float* __restrict__ bias,
                                           bf16_t* __restrict__ outLds,
                                           bf16_t (&As)[2][2048],
                                           bf16_t (&Bs)[2][8192]) {
    const int tid = threadIdx.x;
    const int lane = tid & 63;
    const int w = tid >> 6;
    const int lr = lane & 15;
    const int lk = (lane >> 4) << 3;
    const int srow = tid >> 2;            // staging row 0..63
    const int scolE = (tid & 3) << 3;

    const bf16_t* pB = W + (long)srow * 512 + scolE;
    const bf16_t* pA = nullptr;
    if constexpr (AG) pA = Ag + (long)srow * 512 + scolE;
    char* ldsB = (char*)&Bs[0][0] + (w << 10);
    char* ldsA = (char*)&As[0][0] + (w << 10);

    auto stage = [&](int buf, int kt) {
        if constexpr (AG) GLD16(pA + kt, ldsA + (buf << 12));
        GLD16(pB + kt,             ldsB + (buf << 14));
        GLD16(pB + 64 * 512 + kt,  ldsB + (buf << 14) + 4096);
        GLD16(pB + 128 * 512 + kt, ldsB + (buf << 14) + 8192);
        GLD16(pB + 192 * 512 + kt, ldsB + (buf << 14) + 12288);
    };

    f32x4 acc[NM][4];
    const f32x4 zero = {0.f, 0.f, 0.f, 0.f};
#pragma unroll
    for (int i = 0; i < NM; ++i)
#pragma unroll
        for (int j = 0; j < 4; ++j) acc[i][j] = zero;

    stage(0, 0);
    WAIT0_BAR();
    for (int t = 0; t < 16; ++t) {
        const int cur = t & 1, kt = t << 5;
        if (t < 15) stage(cur ^ 1, (t + 1) << 5);

        bf16x8 af[NM], bfr[4];
#pragma unroll
        for (int mi = 0; mi < NM; ++mi) {
            if constexpr (AG)
                af[mi] = *(const bf16x8*)&As[cur][(((mi << 4) + lr) << 5) + lk];
            else
                af[mi] = *(const bf16x8*)&Alds[((mi << 4) + lr) * 512 + kt + lk];
        }
#pragma unroll
        for (int nt = 0; nt < 4; ++nt)
            bfr[nt] = *(const bf16x8*)&Bs[cur][(((w << 6) + (nt << 4) + lr) << 5) + lk];
#pragma unroll
        for (int mi = 0; mi < NM; ++mi)
#pragma unroll
            for (int nt = 0; nt < 4; ++nt)
                acc[mi][nt] = __builtin_amdgcn_mfma_f32_16x16x32_bf16(
                    af[mi], bfr[nt], acc[mi][nt], 0, 0, 0);

        if (t < 15) WAIT0_BAR();
    }

    const int crow = (lane >> 4) << 2;
#pragma unroll
    for (int nt = 0; nt < 4; ++nt) {
        int col = (w << 6) + (nt << 4) + lr;
        float bv = bias[col];
#pragma unroll
        for (int mi = 0; mi < NM; ++mi)
#pragma unroll
            for (int r = 0; r < 4; ++r) {
                int row = (mi << 4) + crow + r;
                outLds[row * 256 + col] = f2bf(tanh_fast(acc[mi][nt][r] + bv));
            }
    }
}

__global__ void __launch_bounds__(256) tail_kernel(const bf16_t* __restrict__ src,
                                                   const bf16_t* __restrict__ W,
                                                   const float* __restrict__ bias,
                                                   const float* __restrict__ WFw,
                                                   const float* __restrict__ WFb,
                                                   const float* __restrict__ WOw,
                                                   const float* __restrict__ WOb,
                                                   float* __restrict__ out) {
    __shared__ __align__(16) bf16_t As[2][2048];
    __shared__ __align__(16) bf16_t Bs[2][8192];
    __shared__ __align__(16) bf16_t chunkA[16384];   // 64x256
    __shared__ __align__(16) bf16_t chunkB[8192];    // 32x256
    __shared__ float hid[2048];                      // 8x256

    const bf16_t* Ag = src + (long)blockIdx.x * 32768;   // 128 rows x 256

    tail_level<4, true>(Ag, nullptr, W, bias, chunkA, As, Bs);   // -> 64 rows
    __syncthreads();
    tail_level<2, false>(nullptr, chunkA, W, bias, chunkB, As, Bs);  // -> 32
    __syncthreads();
    tail_level<1, false>(nullptr, chunkB, W, bias, chunkA, As, Bs);  // -> 16
    __syncthreads();
    tail_level<1, false>(nullptr, chunkA, W, bias, chunkB, As, Bs);  // -> 8 valid
    __syncthreads();

    // head: hidden = relu(root @ WF^T + bF); out = hidden @ WO^T + bO
    // root = chunkB rows 0..7 (bf16)
    const int t = threadIdx.x;        // t = hidden column
    float s[8];
#pragma unroll
    for (int r = 0; r < 8; ++r) s[r] = 0.f;
    const float4* wf4 = (const float4*)(WFw + (long)t * 256);
#pragma unroll 4
    for (int k4 = 0; k4 < 64; ++k4) {
        float4 wv = wf4[k4];
        int k = k4 << 2;
#pragma unroll
        for (int r = 0; r < 8; ++r) {
            bf16x4 rv = *(const bf16x4*)&chunkB[r * 256 + k];
            s[r] += (float)rv[0] * wv.x + (float)rv[1] * wv.y +
                    (float)rv[2] * wv.z + (float)rv[3] * wv.w;
        }
    }
    float bf_ = WFb[t];
#pragma unroll
    for (int r = 0; r < 8; ++r) hid[r * 256 + t] = fmaxf(s[r] + bf_, 0.f);
    __syncthreads();

    if (t < 40) {
        int r = t / 5, cls = t % 5;
        float s2 = WOb[cls];
        const float* wo = WOw + cls * 256;
        const float* hr = hid + r * 256;
        for (int k = 0; k < 256; ++k) s2 += hr[k] * wo[k];
        out[((long)blockIdx.x * 8 + r) * 5 + cls] = s2;
    }
}

// ---------------------------------------------------------------------------
extern "C" void kernel_launch(void* const* d_in, const int* in_sizes, int n_in,
                              void* d_out, int out_size, void* d_ws, size_t ws_size,
                              hipStream_t stream) {
    const int*   tokens = (const int*)d_in[0];
    const float* table  = (const float*)d_in[1];
    const float* WRw    = (const float*)d_in[2];
    const float* WRb    = (const float*)d_in[3];
    const float* WFw    = (const float*)d_in[4];
    const float* WFb    = (const float*)d_in[5];
    const float* WOw    = (const float*)d_in[6];
    const float* WOb    = (const float*)d_in[7];
    float* out = (float*)d_out;

    char* ws = (char*)d_ws;
    bf16_t* tableBf = (bf16_t*)ws;                        // 32000*256*2 = 16.4 MB
    bf16_t* Wbf  = (bf16_t*)(ws + (size_t)20971520);      // 256 KB
    bf16_t* buf0 = (bf16_t*)(ws + (size_t)25165824);      // up to 33.6 MB
    bf16_t* buf1 = (bf16_t*)(ws + (size_t)67108864);      // up to 16.8 MB

    cvt_kernel<<<8000, 256, 0, stream>>>(table, tableBf);  // 32000*256/1024
    cvt_kernel<<<128, 256, 0, stream>>>(WRw, Wbf);         // 131072/1024

    // level 1 (out 65536 rows): gather A straight from bf16 table
    level_gemm<true><<<dim3(512, 2), 256, 0, stream>>>(nullptr, tokens, tableBf,
                                                       Wbf, WRb, buf0);
    // levels 2..5 (out 32768, 16384, 8192, 4096 rows)
    level_gemm<false><<<dim3(256, 2), 256, 0, stream>>>(buf0, nullptr, nullptr,
                                                        Wbf, WRb, buf1);
    level_gemm<false><<<dim3(128, 2), 256, 0, stream>>>(buf1, nullptr, nullptr,
                                                        Wbf, WRb, buf0);
    level_gemm<false><<<dim3(64, 2), 256, 0, stream>>>(buf0, nullptr, nullptr,
                                                       Wbf, WRb, buf1);
    level_gemm<false><<<dim3(32, 2), 256, 0, stream>>>(buf1, nullptr, nullptr,
                                                       Wbf, WRb, buf0);
    // levels 6..9 (2048..256) + head, fused
    tail_kernel<<<32, 256, 0, stream>>>(buf0, Wbf, WRb, WFw, WFb, WOw, WOb, out);
}

// Round 3
// 206.847 us; speedup vs baseline: 1.2765x; 1.0224x over previous
//
#include <hip/hip_runtime.h>
#include <hip/hip_bf16.h>

typedef __bf16 bf16_t;
typedef __bf16 bf16x8 __attribute__((ext_vector_type(8)));
typedef __bf16 bf16x4 __attribute__((ext_vector_type(4)));
typedef float f32x4 __attribute__((ext_vector_type(4)));

__device__ __forceinline__ bf16_t f2bf(float f) {
    __hip_bfloat16 h = __float2bfloat16(f);   // RNE
    return __builtin_bit_cast(bf16_t, h);
}

__device__ __forceinline__ float tanh_fast(float s) {
    float e2x = __expf(2.0f * s);
    return 1.0f - 2.0f * __builtin_amdgcn_rcpf(e2x + 1.0f);
}

// 16B-unit XOR swizzle (involution): spreads 64B-row-stride reads over banks
__device__ __forceinline__ int swz(int u) { return u ^ ((u >> 3) & 7); }

// async global->LDS, 16B/lane, LDS dest = wave-uniform base + lane*16,
// global src per-lane.
#define GLD16(g, l)                                                        \
    __builtin_amdgcn_global_load_lds(                                      \
        (const __attribute__((address_space(1))) void*)(g),                \
        (__attribute__((address_space(3))) void*)(l), 16, 0, 0)

#define WAITV4() asm volatile("s_waitcnt vmcnt(4)" ::: "memory")
#define WAITV0() asm volatile("s_waitcnt vmcnt(0)" ::: "memory")

// ---------------------------------------------------------------------------
// flat f32 -> bf16 convert, 4 elems/thread
__global__ void __launch_bounds__(256) cvt_kernel(const float* __restrict__ src,
                                                  bf16_t* __restrict__ dst) {
    int i = blockIdx.x * 256 + threadIdx.x;
    float4 v = ((const float4*)src)[i];
    bf16x4 o;
    o[0] = f2bf(v.x); o[1] = f2bf(v.y); o[2] = f2bf(v.z); o[3] = f2bf(v.w);
    ((bf16x4*)dst)[i] = o;
}

// ---------------------------------------------------------------------------
// One tree level: out[m,n] = tanh( sum_k A[m,k]*W[n,k] + bias[n] )
// 128x128 tile, BK=32, 3-stage pipeline w/ counted vmcnt, T2-swizzled LDS.
template <bool GATHER>
__global__ void __launch_bounds__(256) level_gemm(const bf16_t* __restrict__ A,
                                                  const int* __restrict__ tokens,
                                                  const bf16_t* __restrict__ tableBf,
                                                  const bf16_t* __restrict__ W,
                                                  const float* __restrict__ bias,
                                                  bf16_t* __restrict__ out) {
    constexpr int K = 512, N = 256;
    __shared__ __align__(16) char lds[49152];   // 3 bufs x (A 8KB + B 8KB)

    const int tid = threadIdx.x;
    const int lane = tid & 63;
    const int w = tid >> 6;
    const int wm = w >> 1, wn = w & 1;
    const long brow = (long)blockIdx.x * 128;
    const int bcol = blockIdx.y * 128;
    const int lr = lane & 15;
    const int g = lane >> 4;

    // ---- staging source (swizzled): LDS unit v holds global unit swz(v)
    const int vlin = (w << 6) | lane;
    const int vs = swz(vlin);
    const int srow = vs >> 2;              // 0..63
    const int scolE = (vs & 3) << 3;       // elem offset 0,8,16,24

    const bf16_t *paLo0, *paHi0, *paLo1, *paHi1, *pa0, *pa1;
    if constexpr (GATHER) {
        long m0 = brow + srow, m1 = m0 + 64;
        int t0a = tokens[2 * m0], t0b = tokens[2 * m0 + 1];
        int t1a = tokens[2 * m1], t1b = tokens[2 * m1 + 1];
        paLo0 = tableBf + (long)t0a * 256 + scolE;
        paHi0 = tableBf + (long)t0b * 256 + scolE;
        paLo1 = tableBf + (long)t1a * 256 + scolE;
        paHi1 = tableBf + (long)t1b * 256 + scolE;
    } else {
        pa0 = A + (brow + srow) * K + scolE;
        pa1 = A + (brow + srow + 64) * K + scolE;
    }
    const bf16_t* pw0 = W + (long)(bcol + srow) * K + scolE;
    const bf16_t* pw1 = pw0 + 64 * K;

    // preload bias BEFORE pipeline so no compiler vmem ops pollute vmcnt
    float bv[4];
#pragma unroll
    for (int nt = 0; nt < 4; ++nt)
        bv[nt] = bias[bcol + (wn << 6) + (nt << 4) + lr];

    // ---- fragment read offsets (swizzled)
    int offA[4], offB[4];
#pragma unroll
    for (int mt = 0; mt < 4; ++mt) {
        int rowA = (wm << 6) + (mt << 4) + lr;
        offA[mt] = swz(rowA * 4 + g) * 16;
    }
#pragma unroll
    for (int nt = 0; nt < 4; ++nt) {
        int rowB = (wn << 6) + (nt << 4) + lr;
        offB[nt] = 8192 + swz(rowB * 4 + g) * 16;
    }

    auto stage = [&](int buf, int kt) {
        char* dA = lds + buf * 16384 + (w << 10);
        char* dB = dA + 8192;
        const bf16_t *s0, *s1;
        if constexpr (GATHER) {
            int klo = kt & 255;
            bool lo = kt < 256;
            s0 = (lo ? paLo0 : paHi0) + klo;
            s1 = (lo ? paLo1 : paHi1) + klo;
        } else {
            s0 = pa0 + kt;
            s1 = pa1 + kt;
        }
        GLD16(s0, dA);
        GLD16(s1, dA + 4096);
        GLD16(pw0 + kt, dB);
        GLD16(pw1 + kt, dB + 4096);
    };

    f32x4 acc[4][4];
    const f32x4 zero = {0.f, 0.f, 0.f, 0.f};
#pragma unroll
    for (int i = 0; i < 4; ++i)
#pragma unroll
        for (int j = 0; j < 4; ++j) acc[i][j] = zero;

    stage(0, 0);
    stage(1, 32);
    WAITV4();                          // stage0 landed; stage1 in flight
    __builtin_amdgcn_s_barrier();

#pragma unroll
    for (int t = 0; t < 16; ++t) {
        const int bufOff = 16384 * (t % 3);
        if (t + 2 < 16) stage((t + 2) % 3, (t + 2) << 5);

        bf16x8 af[4], bfr[4];
#pragma unroll
        for (int mt = 0; mt < 4; ++mt)
            af[mt] = *(const bf16x8*)(lds + bufOff + offA[mt]);
#pragma unroll
        for (int nt = 0; nt < 4; ++nt)
            bfr[nt] = *(const bf16x8*)(lds + bufOff + offB[nt]);
#pragma unroll
        for (int mt = 0; mt < 4; ++mt)
#pragma unroll
            for (int nt = 0; nt < 4; ++nt)
                acc[mt][nt] = __builtin_amdgcn_mfma_f32_16x16x32_bf16(
                    af[mt], bfr[nt], acc[mt][nt], 0, 0, 0);

        if (t < 14) {
            WAITV4();                  // stage t+1 landed; t+2 stays in flight
            __builtin_amdgcn_s_barrier();
        } else if (t == 14) {
            WAITV0();
            __builtin_amdgcn_s_barrier();
        }
    }

    // epilogue: bias + tanh, store bf16. C/D map: col=lane&15, row=(lane>>4)*4+r
    const int crow = g << 2;
#pragma unroll
    for (int nt = 0; nt < 4; ++nt) {
        int col = bcol + (wn << 6) + (nt << 4) + lr;
#pragma unroll
        for (int mt = 0; mt < 4; ++mt) {
            long row0 = brow + (wm << 6) + (mt << 4) + crow;
#pragma unroll
            for (int r = 0; r < 4; ++r)
                out[(row0 + r) * N + col] = f2bf(tanh_fast(acc[mt][nt][r] + bv[nt]));
        }
    }
}

// ---------------------------------------------------------------------------
// Tail: 256 blocks, one batch each. Input 32 rows x 256 from the 8192-row
// buffer; 5 levels (16->8->4->2->1 out-rows) + head. A in padded LDS
// (row stride 520 elems kills the 1KB-stride conflict); W read straight from
// global (L2-hot) into registers -> no barriers inside the K-loop.
__device__ __forceinline__ void tail_level(const char* chIn, char* chOut,
                                           const bf16_t* __restrict__ W,
                                           const float* bv, int w, int lane) {
    const int lr = lane & 15;
    const int g = lane >> 4;
    const char* aBase = chIn + lr * 1040 + g * 16;
    const bf16_t* wBase = W + (long)((w << 6) + lr) * 512 + g * 8;

    f32x4 acc[4];
    const f32x4 zero = {0.f, 0.f, 0.f, 0.f};
#pragma unroll
    for (int nt = 0; nt < 4; ++nt) acc[nt] = zero;

#pragma unroll
    for (int kt = 0; kt < 16; ++kt) {
        bf16x8 af = *(const bf16x8*)(aBase + kt * 64);
#pragma unroll
        for (int nt = 0; nt < 4; ++nt) {
            bf16x8 bfv = *(const bf16x8*)(wBase + (nt << 4) * 512 + kt * 32);
            acc[nt] = __builtin_amdgcn_mfma_f32_16x16x32_bf16(af, bfv, acc[nt], 0, 0, 0);
        }
    }

    const int crow = g << 2;
#pragma unroll
    for (int nt = 0; nt < 4; ++nt) {
        int col = (w << 6) + (nt << 4) + lr;
#pragma unroll
        for (int r = 0; r < 4; ++r) {
            int R = crow + r;                       // out row 0..15
            float vv = tanh_fast(acc[nt][r] + bv[nt]);
            // next level's A layout: A-row R>>1, elem (R&1)*256 + col
            *(bf16_t*)(chOut + (R >> 1) * 1040 + (((R & 1) << 8) + col) * 2) = f2bf(vv);
        }
    }
}

__global__ void __launch_bounds__(256) tail_kernel(const bf16_t* __restrict__ in,
                                                   const bf16_t* __restrict__ W,
                                                   const float* __restrict__ bias,
                                                   const float* __restrict__ WFw,
                                                   const float* __restrict__ WFb,
                                                   const float* __restrict__ WOw,
                                                   const float* __restrict__ WOb,
                                                   float* __restrict__ out) {
    __shared__ __align__(16) char tl[2][16640];   // 16 rows x (512+8) bf16
    __shared__ float hid[256];

    const int tid = threadIdx.x;
    const int lane = tid & 63;
    const int w = tid >> 6;
    const int lr = lane & 15;

    float bv[4];
#pragma unroll
    for (int nt = 0; nt < 4; ++nt) bv[nt] = bias[(w << 6) + (nt << 4) + lr];

    // stage input chunk (32 rows x 256 = 16 A-rows x 512) into padded LDS
    const bf16_t* gin = in + (size_t)blockIdx.x * 8192;
#pragma unroll
    for (int j = 0; j < 4; ++j) {
        int i = j * 256 + tid;                 // 16B unit index 0..1023
        int4 v = *(const int4*)(gin + i * 8);
        *(int4*)(&tl[0][0] + (i >> 6) * 1040 + (i & 63) * 16) = v;
    }
    __syncthreads();

    tail_level(tl[0], tl[1], W, bv, w, lane);  __syncthreads();
    tail_level(tl[1], tl[0], W, bv, w, lane);  __syncthreads();
    tail_level(tl[0], tl[1], W, bv, w, lane);  __syncthreads();
    tail_level(tl[1], tl[0], W, bv, w, lane);  __syncthreads();
    tail_level(tl[0], tl[1], W, bv, w, lane);  __syncthreads();
    // root = tl[1] A-row 0, elems 0..255 (contiguous first 512 bytes)

    const bf16_t* root = (const bf16_t*)&tl[1][0];
    float s = WFb[tid];
    const float4* wf = (const float4*)(WFw + (long)tid * 256);
#pragma unroll 8
    for (int k4 = 0; k4 < 64; ++k4) {
        float4 wv = wf[k4];
        int k = k4 << 2;
        bf16x4 rv = *(const bf16x4*)&root[k];
        s += (float)rv[0] * wv.x + (float)rv[1] * wv.y +
             (float)rv[2] * wv.z + (float)rv[3] * wv.w;
    }
    hid[tid] = fmaxf(s, 0.0f);
    __syncthreads();

    if (tid < 5) {
        float o = WOb[tid];
        const float* wo = WOw + tid * 256;
        for (int k = 0; k < 256; ++k) o += hid[k] * wo[k];
        out[(long)blockIdx.x * 5 + tid] = o;
    }
}

// ---------------------------------------------------------------------------
extern "C" void kernel_launch(void* const* d_in, const int* in_sizes, int n_in,
                              void* d_out, int out_size, void* d_ws, size_t ws_size,
                              hipStream_t stream) {
    const int*   tokens = (const int*)d_in[0];
    const float* table  = (const float*)d_in[1];
    const float* WRw    = (const float*)d_in[2];
    const float* WRb    = (const float*)d_in[3];
    const float* WFw    = (const float*)d_in[4];
    const float* WFb    = (const float*)d_in[5];
    const float* WOw    = (const float*)d_in[6];
    const float* WOb    = (const float*)d_in[7];
    float* out = (float*)d_out;

    char* ws = (char*)d_ws;
    bf16_t* tableBf = (bf16_t*)ws;                        // 16.4 MB
    bf16_t* Wbf  = (bf16_t*)(ws + (size_t)20971520);      // 256 KB
    bf16_t* buf0 = (bf16_t*)(ws + (size_t)25165824);      // <= 33.6 MB
    bf16_t* buf1 = (bf16_t*)(ws + (size_t)67108864);      // <= 16.8 MB

    cvt_kernel<<<8000, 256, 0, stream>>>(table, tableBf);
    cvt_kernel<<<128, 256, 0, stream>>>(WRw, Wbf);

    // L1: 65536 out rows, gather A straight from bf16 table
    level_gemm<true><<<dim3(512, 2), 256, 0, stream>>>(nullptr, tokens, tableBf,
                                                       Wbf, WRb, buf0);
    // L2..L4: 32768, 16384, 8192 out rows
    level_gemm<false><<<dim3(256, 2), 256, 0, stream>>>(buf0, nullptr, nullptr,
                                                        Wbf, WRb, buf1);
    level_gemm<false><<<dim3(128, 2), 256, 0, stream>>>(buf1, nullptr, nullptr,
                                                        Wbf, WRb, buf0);
    level_gemm<false><<<dim3(64, 2), 256, 0, stream>>>(buf0, nullptr, nullptr,
                                                       Wbf, WRb, buf1);
    // L5..L9 (4096..256 rows) + head, fused; 256 blocks x 1 batch
    tail_kernel<<<256, 256, 0, stream>>>(buf1, Wbf, WRb, WFw, WFb, WOw, WOb, out);
}

// Round 4
// 188.571 us; speedup vs baseline: 1.4002x; 1.0969x over previous
//
#include <hip/hip_runtime.h>
#include <hip/hip_bf16.h>

typedef __bf16 bf16_t;
typedef __bf16 bf16x8 __attribute__((ext_vector_type(8)));
typedef __bf16 bf16x4 __attribute__((ext_vector_type(4)));
typedef float f32x4 __attribute__((ext_vector_type(4)));

__device__ __forceinline__ bf16_t f2bf(float f) {
    __hip_bfloat16 h = __float2bfloat16(f);   // RNE
    return __builtin_bit_cast(bf16_t, h);
}

__device__ __forceinline__ float tanh_fast(float s) {
    float e2x = __expf(2.0f * s);
    return 1.0f - 2.0f * __builtin_amdgcn_rcpf(e2x + 1.0f);
}

// 16B-unit XOR swizzle (involution): spreads 64B-row-stride reads over banks
__device__ __forceinline__ int swz(int u) { return u ^ ((u >> 3) & 7); }

// async global->LDS, 16B/lane, LDS dest = wave-uniform base + lane*16,
// global src per-lane.
#define GLD16(g, l)                                                        \
    __builtin_amdgcn_global_load_lds(                                      \
        (const __attribute__((address_space(1))) void*)(g),                \
        (__attribute__((address_space(3))) void*)(l), 16, 0, 0)

#define WAITV4() asm volatile("s_waitcnt vmcnt(4)" ::: "memory")
#define WAITV0() asm volatile("s_waitcnt vmcnt(0)" ::: "memory")

// ---------------------------------------------------------------------------
// Setup: table f32->bf16 (blocks 0..7999), W f32->bf16 row-major (8000..8127),
// W -> MFMA-fragment-order copy Wfrag (8128..8191).
// Wfrag[((n16*16 + kt)*64 + lane)*8 + e] = W[n16*16 + (lane&15)][kt*32 + (lane>>4)*8 + e]
__global__ void __launch_bounds__(256) setup_kernel(const float* __restrict__ table,
                                                    const float* __restrict__ WRw,
                                                    bf16_t* __restrict__ tableBf,
                                                    bf16_t* __restrict__ Wbf,
                                                    bf16_t* __restrict__ Wfrag) {
    const int b = blockIdx.x, tid = threadIdx.x;
    if (b < 8000) {
        int i = b * 256 + tid;
        float4 v = ((const float4*)table)[i];
        bf16x4 o;
        o[0] = f2bf(v.x); o[1] = f2bf(v.y); o[2] = f2bf(v.z); o[3] = f2bf(v.w);
        ((bf16x4*)tableBf)[i] = o;
    } else if (b < 8128) {
        int i = (b - 8000) * 256 + tid;
        float4 v = ((const float4*)WRw)[i];
        bf16x4 o;
        o[0] = f2bf(v.x); o[1] = f2bf(v.y); o[2] = f2bf(v.z); o[3] = f2bf(v.w);
        ((bf16x4*)Wbf)[i] = o;
    } else {
        int gt = (b - 8128) * 256 + tid;        // 0..16383
        int n16 = gt >> 10, rem = gt & 1023;
        int kt = rem >> 6, ln = rem & 63;
        int r = n16 * 16 + (ln & 15);
        int c = kt * 32 + (ln >> 4) * 8;
        const float4* s = (const float4*)(WRw + (long)r * 512 + c);
        float4 v0 = s[0], v1 = s[1];
        bf16x8 o;
        o[0] = f2bf(v0.x); o[1] = f2bf(v0.y); o[2] = f2bf(v0.z); o[3] = f2bf(v0.w);
        o[4] = f2bf(v1.x); o[5] = f2bf(v1.y); o[6] = f2bf(v1.z); o[7] = f2bf(v1.w);
        *(bf16x8*)(Wfrag + (size_t)gt * 8) = o;
    }
}

// ---------------------------------------------------------------------------
// One tree level: out[m,n] = tanh( sum_k A[m,k]*W[n,k] + bias[n] )
// 128x128 tile, BK=32, 3-stage pipeline w/ counted vmcnt, T2-swizzled LDS.
template <bool GATHER>
__global__ void __launch_bounds__(256) level_gemm(const bf16_t* __restrict__ A,
                                                  const int* __restrict__ tokens,
                                                  const bf16_t* __restrict__ tableBf,
                                                  const bf16_t* __restrict__ W,
                                                  const float* __restrict__ bias,
                                                  bf16_t* __restrict__ out) {
    constexpr int K = 512, N = 256;
    __shared__ __align__(16) char lds[49152];   // 3 bufs x (A 8KB + B 8KB)

    const int tid = threadIdx.x;
    const int lane = tid & 63;
    const int w = tid >> 6;
    const int wm = w >> 1, wn = w & 1;
    const long brow = (long)blockIdx.x * 128;
    const int bcol = blockIdx.y * 128;
    const int lr = lane & 15;
    const int g = lane >> 4;

    // ---- staging source (swizzled): LDS unit v holds global unit swz(v)
    const int vlin = (w << 6) | lane;
    const int vs = swz(vlin);
    const int srow = vs >> 2;              // 0..63
    const int scolE = (vs & 3) << 3;       // elem offset 0,8,16,24

    const bf16_t *paLo0, *paHi0, *paLo1, *paHi1, *pa0, *pa1;
    if constexpr (GATHER) {
        long m0 = brow + srow, m1 = m0 + 64;
        int t0a = tokens[2 * m0], t0b = tokens[2 * m0 + 1];
        int t1a = tokens[2 * m1], t1b = tokens[2 * m1 + 1];
        paLo0 = tableBf + (long)t0a * 256 + scolE;
        paHi0 = tableBf + (long)t0b * 256 + scolE;
        paLo1 = tableBf + (long)t1a * 256 + scolE;
        paHi1 = tableBf + (long)t1b * 256 + scolE;
    } else {
        pa0 = A + (brow + srow) * K + scolE;
        pa1 = A + (brow + srow + 64) * K + scolE;
    }
    const bf16_t* pw0 = W + (long)(bcol + srow) * K + scolE;
    const bf16_t* pw1 = pw0 + 64 * K;

    // preload bias BEFORE pipeline so no compiler vmem ops pollute vmcnt
    float bv[4];
#pragma unroll
    for (int nt = 0; nt < 4; ++nt)
        bv[nt] = bias[bcol + (wn << 6) + (nt << 4) + lr];

    // ---- fragment read offsets (swizzled)
    int offA[4], offB[4];
#pragma unroll
    for (int mt = 0; mt < 4; ++mt) {
        int rowA = (wm << 6) + (mt << 4) + lr;
        offA[mt] = swz(rowA * 4 + g) * 16;
    }
#pragma unroll
    for (int nt = 0; nt < 4; ++nt) {
        int rowB = (wn << 6) + (nt << 4) + lr;
        offB[nt] = 8192 + swz(rowB * 4 + g) * 16;
    }

    auto stage = [&](int buf, int kt) {
        char* dA = lds + buf * 16384 + (w << 10);
        char* dB = dA + 8192;
        const bf16_t *s0, *s1;
        if constexpr (GATHER) {
            int klo = kt & 255;
            bool lo = kt < 256;
            s0 = (lo ? paLo0 : paHi0) + klo;
            s1 = (lo ? paLo1 : paHi1) + klo;
        } else {
            s0 = pa0 + kt;
            s1 = pa1 + kt;
        }
        GLD16(s0, dA);
        GLD16(s1, dA + 4096);
        GLD16(pw0 + kt, dB);
        GLD16(pw1 + kt, dB + 4096);
    };

    f32x4 acc[4][4];
    const f32x4 zero = {0.f, 0.f, 0.f, 0.f};
#pragma unroll
    for (int i = 0; i < 4; ++i)
#pragma unroll
        for (int j = 0; j < 4; ++j) acc[i][j] = zero;

    stage(0, 0);
    stage(1, 32);
    WAITV4();                          // stage0 landed; stage1 in flight
    __builtin_amdgcn_s_barrier();

#pragma unroll
    for (int t = 0; t < 16; ++t) {
        const int bufOff = 16384 * (t % 3);
        if (t + 2 < 16) stage((t + 2) % 3, (t + 2) << 5);

        bf16x8 af[4], bfr[4];
#pragma unroll
        for (int mt = 0; mt < 4; ++mt)
            af[mt] = *(const bf16x8*)(lds + bufOff + offA[mt]);
#pragma unroll
        for (int nt = 0; nt < 4; ++nt)
            bfr[nt] = *(const bf16x8*)(lds + bufOff + offB[nt]);
#pragma unroll
        for (int mt = 0; mt < 4; ++mt)
#pragma unroll
            for (int nt = 0; nt < 4; ++nt)
                acc[mt][nt] = __builtin_amdgcn_mfma_f32_16x16x32_bf16(
                    af[mt], bfr[nt], acc[mt][nt], 0, 0, 0);

        if (t < 14) {
            WAITV4();                  // stage t+1 landed; t+2 stays in flight
            __builtin_amdgcn_s_barrier();
        } else if (t == 14) {
            WAITV0();
            __builtin_amdgcn_s_barrier();
        }
    }

    // epilogue: bias + tanh, store bf16. C/D map: col=lane&15, row=(lane>>4)*4+r
    const int crow = g << 2;
#pragma unroll
    for (int nt = 0; nt < 4; ++nt) {
        int col = bcol + (wn << 6) + (nt << 4) + lr;
#pragma unroll
        for (int mt = 0; mt < 4; ++mt) {
            long row0 = brow + (wm << 6) + (mt << 4) + crow;
#pragma unroll
            for (int r = 0; r < 4; ++r)
                out[(row0 + r) * N + col] = f2bf(tanh_fast(acc[mt][nt][r] + bv[nt]));
        }
    }
}

// ---------------------------------------------------------------------------
// Tail: 256 blocks, one batch each. Input 32 rows x 256 from the 8192-row
// buffer; 5 levels (16->8->4->2->1 out-rows) + head. A in padded LDS;
// W fragments read COALESCED from the pre-swizzled Wfrag (1KB/wave/load,
// L2-resident) -> no barriers, no strided lanes.
__device__ __forceinline__ void tail_level(const char* chIn, char* chOut,
                                           const bf16_t* __restrict__ wfBase,
                                           const float* bv, int lane) {
    const int lr = lane & 15;
    const int g = lane >> 4;
    const char* aBase = chIn + lr * 1040 + g * 16;

    f32x4 acc[4];
    const f32x4 zero = {0.f, 0.f, 0.f, 0.f};
#pragma unroll
    for (int nt = 0; nt < 4; ++nt) acc[nt] = zero;

#pragma unroll
    for (int kt = 0; kt < 16; ++kt) {
        bf16x8 af = *(const bf16x8*)(aBase + kt * 64);
#pragma unroll
        for (int nt = 0; nt < 4; ++nt) {
            // fragment (nt,kt): contiguous 1KB across the wave
            bf16x8 bfv = *(const bf16x8*)(wfBase + ((nt << 4) + kt) * 512);
            acc[nt] = __builtin_amdgcn_mfma_f32_16x16x32_bf16(af, bfv, acc[nt], 0, 0, 0);
        }
    }

    const int crow = g << 2;
#pragma unroll
    for (int nt = 0; nt < 4; ++nt) {
#pragma unroll
        for (int r = 0; r < 4; ++r) {
            int R = crow + r;                       // out row 0..15
            float vv = tanh_fast(acc[nt][r] + bv[nt]);
            // col index is carried by wfBase's wave offset: col = w*64+nt*16+lr,
            // but we only need the LDS slot, computed by caller-passed bv/col.
            // next level's A layout: A-row R>>1, elem (R&1)*256 + col
            ((void)0);
            // store handled below via col passed in bv-parallel array
            // (placeholder removed — see caller macro)
        }
    }
    // NOTE: epilogue needs col; done inline here using lane+wave encoded in bv.
    // To keep col available we recompute it from wfBase? Simpler: caller passes w.
}

// (tail_level with explicit w for the epilogue)
__device__ __forceinline__ void tail_level_w(const char* chIn, char* chOut,
                                             const bf16_t* __restrict__ wfBase,
                                             const float* bv, int w, int lane) {
    const int lr = lane & 15;
    const int g = lane >> 4;
    const char* aBase = chIn + lr * 1040 + g * 16;

    f32x4 acc[4];
    const f32x4 zero = {0.f, 0.f, 0.f, 0.f};
#pragma unroll
    for (int nt = 0; nt < 4; ++nt) acc[nt] = zero;

#pragma unroll
    for (int kt = 0; kt < 16; ++kt) {
        bf16x8 af = *(const bf16x8*)(aBase + kt * 64);
#pragma unroll
        for (int nt = 0; nt < 4; ++nt) {
            bf16x8 bfv = *(const bf16x8*)(wfBase + ((nt << 4) + kt) * 512);
            acc[nt] = __builtin_amdgcn_mfma_f32_16x16x32_bf16(af, bfv, acc[nt], 0, 0, 0);
        }
    }

    const int crow = g << 2;
#pragma unroll
    for (int nt = 0; nt < 4; ++nt) {
        int col = (w << 6) + (nt << 4) + lr;
#pragma unroll
        for (int r = 0; r < 4; ++r) {
            int R = crow + r;                       // out row 0..15
            float vv = tanh_fast(acc[nt][r] + bv[nt]);
            *(bf16_t*)(chOut + (R >> 1) * 1040 + (((R & 1) << 8) + col) * 2) = f2bf(vv);
        }
    }
}

__global__ void __launch_bounds__(256) tail_kernel(const bf16_t* __restrict__ in,
                                                   const bf16_t* __restrict__ Wfrag,
                                                   const float* __restrict__ bias,
                                                   const float* __restrict__ WFw,
                                                   const float* __restrict__ WFb,
                                                   const float* __restrict__ WOw,
                                                   const float* __restrict__ WOb,
                                                   float* __restrict__ out) {
    __shared__ __align__(16) char tl[2][16640];   // 16 rows x (512+8) bf16
    __shared__ float hid[256];

    const int tid = threadIdx.x;
    const int lane = tid & 63;
    const int w = tid >> 6;
    const int lr = lane & 15;

    float bv[4];
#pragma unroll
    for (int nt = 0; nt < 4; ++nt) bv[nt] = bias[(w << 6) + (nt << 4) + lr];

    // wave w's fragment base: n16 = w*4 (+nt), each frag = 512 elems
    const bf16_t* wfBase = Wfrag + ((size_t)((w << 2) << 4) << 6) * 8 / 8;
    wfBase = Wfrag + (size_t)(((w << 2) * 16) * 64 + lane) * 8;

    // stage input chunk (32 rows x 256 = 16 A-rows x 512) into padded LDS
    const bf16_t* gin = in + (size_t)blockIdx.x * 8192;
#pragma unroll
    for (int j = 0; j < 4; ++j) {
        int i = j * 256 + tid;                 // 16B unit index 0..1023
        int4 v = *(const int4*)(gin + i * 8);
        *(int4*)(&tl[0][0] + (i >> 6) * 1040 + (i & 63) * 16) = v;
    }
    __syncthreads();

    tail_level_w(tl[0], tl[1], wfBase, bv, w, lane);  __syncthreads();
    tail_level_w(tl[1], tl[0], wfBase, bv, w, lane);  __syncthreads();
    tail_level_w(tl[0], tl[1], wfBase, bv, w, lane);  __syncthreads();
    tail_level_w(tl[1], tl[0], wfBase, bv, w, lane);  __syncthreads();
    tail_level_w(tl[0], tl[1], wfBase, bv, w, lane);  __syncthreads();
    // root = tl[1] A-row 0, elems 0..255 (contiguous first 512 bytes)

    const bf16_t* root = (const bf16_t*)&tl[1][0];
    float s = WFb[tid];
    const float4* wf = (const float4*)(WFw + (long)tid * 256);
#pragma unroll 8
    for (int k4 = 0; k4 < 64; ++k4) {
        float4 wv = wf[k4];
        int k = k4 << 2;
        bf16x4 rv = *(const bf16x4*)&root[k];
        s += (float)rv[0] * wv.x + (float)rv[1] * wv.y +
             (float)rv[2] * wv.z + (float)rv[3] * wv.w;
    }
    hid[tid] = fmaxf(s, 0.0f);
    __syncthreads();

    if (tid < 5) {
        float o = WOb[tid];
        const float* wo = WOw + tid * 256;
        for (int k = 0; k < 256; ++k) o += hid[k] * wo[k];
        out[(long)blockIdx.x * 5 + tid] = o;
    }
}

// ---------------------------------------------------------------------------
extern "C" void kernel_launch(void* const* d_in, const int* in_sizes, int n_in,
                              void* d_out, int out_size, void* d_ws, size_t ws_size,
                              hipStream_t stream) {
    const int*   tokens = (const int*)d_in[0];
    const float* table  = (const float*)d_in[1];
    const float* WRw    = (const float*)d_in[2];
    const float* WRb    = (const float*)d_in[3];
    const float* WFw    = (const float*)d_in[4];
    const float* WFb    = (const float*)d_in[5];
    const float* WOw    = (const float*)d_in[6];
    const float* WOb    = (const float*)d_in[7];
    float* out = (float*)d_out;

    char* ws = (char*)d_ws;
    bf16_t* tableBf = (bf16_t*)ws;                        // 16.4 MB
    bf16_t* Wbf   = (bf16_t*)(ws + (size_t)20971520);     // 256 KB
    bf16_t* Wfrag = (bf16_t*)(ws + (size_t)22020096);     // 256 KB
    bf16_t* buf0  = (bf16_t*)(ws + (size_t)25165824);     // <= 33.6 MB
    bf16_t* buf1  = (bf16_t*)(ws + (size_t)67108864);     // <= 16.8 MB

    setup_kernel<<<8192, 256, 0, stream>>>(table, WRw, tableBf, Wbf, Wfrag);

    // L1: 65536 out rows, gather A straight from bf16 table
    level_gemm<true><<<dim3(512, 2), 256, 0, stream>>>(nullptr, tokens, tableBf,
                                                       Wbf, WRb, buf0);
    // L2..L4: 32768, 16384, 8192 out rows
    level_gemm<false><<<dim3(256, 2), 256, 0, stream>>>(buf0, nullptr, nullptr,
                                                        Wbf, WRb, buf1);
    level_gemm<false><<<dim3(128, 2), 256, 0, stream>>>(buf1, nullptr, nullptr,
                                                        Wbf, WRb, buf0);
    level_gemm<false><<<dim3(64, 2), 256, 0, stream>>>(buf0, nullptr, nullptr,
                                                       Wbf, WRb, buf1);
    // L5..L9 (4096..256 rows) + head, fused; 256 blocks x 1 batch
    tail_kernel<<<256, 256, 0, stream>>>(buf1, Wfrag, WRb, WFw, WFb, WOw, WOb, out);
}

// Round 5
// 159.165 us; speedup vs baseline: 1.6588x; 1.1848x over previous
//
#include <hip/hip_runtime.h>
#include <hip/hip_bf16.h>

typedef __bf16 bf16_t;
typedef __bf16 bf16x8 __attribute__((ext_vector_type(8)));
typedef __bf16 bf16x4 __attribute__((ext_vector_type(4)));
typedef float f32x4 __attribute__((ext_vector_type(4)));

__device__ __forceinline__ bf16_t f2bf(float f) {
    __hip_bfloat16 h = __float2bfloat16(f);   // RNE
    return __builtin_bit_cast(bf16_t, h);
}

__device__ __forceinline__ float tanh_fast(float s) {
    float e2x = __expf(2.0f * s);
    return 1.0f - 2.0f * __builtin_amdgcn_rcpf(e2x + 1.0f);
}

// 16B-unit XOR swizzle within 64-unit groups (involution)
__device__ __forceinline__ int swz(int u) { return u ^ ((u >> 3) & 7); }
// act-buffer byte-address swizzle: spreads 1KB/2KB/4KB/8KB row strides over banks
__device__ __forceinline__ int actswz(int a) {
    return a ^ ((((a >> 10) ^ (a >> 13)) & 7) << 4);
}

#define GLD16(g, l)                                                        \
    __builtin_amdgcn_global_load_lds(                                      \
        (const __attribute__((address_space(1))) void*)(g),                \
        (__attribute__((address_space(3))) void*)(l), 16, 0, 0)

#define WAITV3() asm volatile("s_waitcnt vmcnt(3)" ::: "memory")
#define WAITV2() asm volatile("s_waitcnt vmcnt(2)" ::: "memory")
#define WAITV0() asm volatile("s_waitcnt vmcnt(0)" ::: "memory")
#define BAR() __builtin_amdgcn_s_barrier()

// ---------------------------------------------------------------------------
// Setup: blocks 0..7999 table cvt; 8000..8127 Wbf; 8128..8191 Wfrag;
// 8192..8255 WFwT transpose (f32).
__global__ void __launch_bounds__(256) setup_kernel(const float* __restrict__ table,
                                                    const float* __restrict__ WRw,
                                                    const float* __restrict__ WFw,
                                                    bf16_t* __restrict__ tableBf,
                                                    bf16_t* __restrict__ Wbf,
                                                    bf16_t* __restrict__ Wfrag,
                                                    float* __restrict__ WFwT) {
    const int b = blockIdx.x, tid = threadIdx.x;
    if (b < 8000) {
        int i = b * 256 + tid;
        float4 v = ((const float4*)table)[i];
        bf16x4 o;
        o[0] = f2bf(v.x); o[1] = f2bf(v.y); o[2] = f2bf(v.z); o[3] = f2bf(v.w);
        ((bf16x4*)tableBf)[i] = o;
    } else if (b < 8128) {
        int i = (b - 8000) * 256 + tid;
        float4 v = ((const float4*)WRw)[i];
        bf16x4 o;
        o[0] = f2bf(v.x); o[1] = f2bf(v.y); o[2] = f2bf(v.z); o[3] = f2bf(v.w);
        ((bf16x4*)Wbf)[i] = o;
    } else if (b < 8192) {
        int gt = (b - 8128) * 256 + tid;        // 0..16383
        int n16 = gt >> 10, rem = gt & 1023;
        int kt = rem >> 6, ln = rem & 63;
        int r = n16 * 16 + (ln & 15);
        int c = kt * 32 + (ln >> 4) * 8;
        const float4* s = (const float4*)(WRw + (long)r * 512 + c);
        float4 v0 = s[0], v1 = s[1];
        bf16x8 o;
        o[0] = f2bf(v0.x); o[1] = f2bf(v0.y); o[2] = f2bf(v0.z); o[3] = f2bf(v0.w);
        o[4] = f2bf(v1.x); o[5] = f2bf(v1.y); o[6] = f2bf(v1.z); o[7] = f2bf(v1.w);
        *(bf16x8*)(Wfrag + (size_t)gt * 8) = o;
    } else {
        int i0 = (b - 8192) * 1024 + tid * 4;   // WFwT[k*256+t] = WFw[t*256+k]
        float4 v;
        v.x = WFw[((i0 + 0) & 255) * 256 + ((i0 + 0) >> 8)];
        v.y = WFw[((i0 + 1) & 255) * 256 + ((i0 + 1) >> 8)];
        v.z = WFw[((i0 + 2) & 255) * 256 + ((i0 + 2) >> 8)];
        v.w = WFw[((i0 + 3) & 255) * 256 + ((i0 + 3) >> 8)];
        *(float4*)(WFwT + i0) = v;
    }
}

// ---------------------------------------------------------------------------
// L1: out[m,n] = tanh(sum_k A[m,k] W[n,k] + b[n]), A gathered from table.
// Tile 128(M) x 256(N=full), BK=32, 512 thr (8 waves 2Mx4N), 3-stage pipeline.
__global__ void __launch_bounds__(512) l1_kernel(const int* __restrict__ tokens,
                                                 const bf16_t* __restrict__ tableBf,
                                                 const bf16_t* __restrict__ W,
                                                 const float* __restrict__ bias,
                                                 bf16_t* __restrict__ out) {
    __shared__ __align__(16) char lds[73728];   // 3 x (A 8KB + B 16KB)
    const int tid = threadIdx.x, lane = tid & 63, w = tid >> 6;
    const int wm = w >> 2, wn = w & 3, lr = lane & 15, g = lane >> 4;
    const long brow = (long)blockIdx.x * 128;

    // A staging: wave w covers units [64w,64w+64); src unit swizzled
    const int ua = (w << 6) + swz(lane);
    const int arow = ua >> 2, acolE = (ua & 3) << 3;
    const long m = brow + arow;
    const int tokA = tokens[2 * m], tokB = tokens[2 * m + 1];
    const bf16_t* paLo = tableBf + (long)tokA * 256 + acolE;
    const bf16_t* paHi = tableBf + (long)tokB * 256 + acolE;

    // B staging: wave w issues 2: units [64w,..) and [64(w+8),..)
    const int ub0 = (w << 6) + swz(lane);
    const int ub1 = ((w + 8) << 6) + swz(lane);
    const bf16_t* pb0 = W + (long)(ub0 >> 2) * 512 + ((ub0 & 3) << 3);
    const bf16_t* pb1 = W + (long)(ub1 >> 2) * 512 + ((ub1 & 3) << 3);

    float bv[4];
#pragma unroll
    for (int nt = 0; nt < 4; ++nt) bv[nt] = bias[(wn << 6) + (nt << 4) + lr];

    int offA[4], offB[4];
#pragma unroll
    for (int mt = 0; mt < 4; ++mt)
        offA[mt] = swz((((wm << 6) + (mt << 4) + lr) << 2) + g) << 4;
#pragma unroll
    for (int nt = 0; nt < 4; ++nt)
        offB[nt] = 8192 + (swz((((wn << 6) + (nt << 4) + lr) << 2) + g) << 4);

    auto stage = [&](int s, int kt) {
        char* base = lds + s * 24576;
        bool lo = kt < 256;
        GLD16((lo ? paLo : paHi) + (kt & 255), base + (w << 10));
        GLD16(pb0 + kt, base + 8192 + (w << 10));
        GLD16(pb1 + kt, base + 8192 + ((w + 8) << 10));
    };

    f32x4 acc[4][4];
    const f32x4 zero = {0.f, 0.f, 0.f, 0.f};
#pragma unroll
    for (int i = 0; i < 4; ++i)
#pragma unroll
        for (int j = 0; j < 4; ++j) acc[i][j] = zero;

    stage(0, 0);
    stage(1, 32);
    WAITV3(); BAR();

#pragma unroll
    for (int t = 0; t < 16; ++t) {
        const char* base = lds + (t % 3) * 24576;
        if (t + 2 < 16) stage((t + 2) % 3, (t + 2) << 5);
        bf16x8 af[4], bfr[4];
#pragma unroll
        for (int mt = 0; mt < 4; ++mt) af[mt] = *(const bf16x8*)(base + offA[mt]);
#pragma unroll
        for (int nt = 0; nt < 4; ++nt) bfr[nt] = *(const bf16x8*)(base + offB[nt]);
#pragma unroll
        for (int mt = 0; mt < 4; ++mt)
#pragma unroll
            for (int nt = 0; nt < 4; ++nt)
                acc[mt][nt] = __builtin_amdgcn_mfma_f32_16x16x32_bf16(
                    af[mt], bfr[nt], acc[mt][nt], 0, 0, 0);
        if (t < 14)      { WAITV3(); BAR(); }
        else if (t == 14){ WAITV0(); BAR(); }
    }

    const int crow = g << 2;
#pragma unroll
    for (int nt = 0; nt < 4; ++nt) {
        int col = (wn << 6) + (nt << 4) + lr;
#pragma unroll
        for (int mt = 0; mt < 4; ++mt) {
            long row0 = brow + (wm << 6) + (mt << 4) + crow;
#pragma unroll
            for (int r = 0; r < 4; ++r)
                out[(row0 + r) * 256 + col] = f2bf(tanh_fast(acc[mt][nt][r] + bv[nt]));
        }
    }
}

// ---------------------------------------------------------------------------
// tree_kernel: 256 blocks (one batch), 512 thr. L2 (A streamed from l1out),
// L3, L4 in LDS act (in-place stride doubling), L5..L9 with W in VGPRs, head.
__global__ void __launch_bounds__(512) tree_kernel(const bf16_t* __restrict__ l1out,
                                                   const bf16_t* __restrict__ W,
                                                   const bf16_t* __restrict__ Wfrag,
                                                   const float* __restrict__ bias,
                                                   const float* __restrict__ WFwT,
                                                   const float* __restrict__ WFb,
                                                   const float* __restrict__ WOw,
                                                   const float* __restrict__ WOb,
                                                   float* __restrict__ out) {
    __shared__ __align__(16) char stg[73728];
    __shared__ __align__(16) char act[65536];
    __shared__ float hid[256];

    const int tid = threadIdx.x, lane = tid & 63, w = tid >> 6;
    const int wm = w >> 2, wn = w & 3, lr = lane & 15, g = lane >> 4;
    const int crow = g << 2;
    const bf16_t* Abase = l1out + (size_t)blockIdx.x * 65536;

    // staging sources (same unit scheme as l1)
    const int ua = (w << 6) + swz(lane);
    const bf16_t* pa = Abase + (long)(ua >> 2) * 512 + ((ua & 3) << 3);
    const int ub0 = (w << 6) + swz(lane);
    const int ub1 = ((w + 8) << 6) + swz(lane);
    const bf16_t* pb0 = W + (long)(ub0 >> 2) * 512 + ((ub0 & 3) << 3);
    const bf16_t* pb1 = W + (long)(ub1 >> 2) * 512 + ((ub1 & 3) << 3);

    float bv[4];                                  // GEMM-phase bias (wn cols)
#pragma unroll
    for (int nt = 0; nt < 4; ++nt) bv[nt] = bias[(wn << 6) + (nt << 4) + lr];
    float bvT[2];                                 // tail-phase bias (w*32 cols)
#pragma unroll
    for (int nt = 0; nt < 2; ++nt) bvT[nt] = bias[(w << 5) + (nt << 4) + lr];

    int offB[4];
#pragma unroll
    for (int nt = 0; nt < 4; ++nt)
        offB[nt] = swz((((wn << 6) + (nt << 4) + lr) << 2) + g) << 4;

    // ================= L2: M=128, A+B staged, out -> act[512*m .. +512) ====
    {
        int offA[4];
#pragma unroll
        for (int mt = 0; mt < 4; ++mt)
            offA[mt] = swz((((wm << 6) + (mt << 4) + lr) << 2) + g) << 4;

        auto stage = [&](int s, int kt) {
            char* base = stg + s * 24576;
            GLD16(pa + kt, base + (w << 10));
            GLD16(pb0 + kt, base + 8192 + (w << 10));
            GLD16(pb1 + kt, base + 8192 + ((w + 8) << 10));
        };

        f32x4 acc[4][4];
        const f32x4 zero = {0.f, 0.f, 0.f, 0.f};
#pragma unroll
        for (int i = 0; i < 4; ++i)
#pragma unroll
            for (int j = 0; j < 4; ++j) acc[i][j] = zero;

        stage(0, 0); stage(1, 32);
        WAITV3(); BAR();
#pragma unroll
        for (int t = 0; t < 16; ++t) {
            const char* base = stg + (t % 3) * 24576;
            if (t + 2 < 16) stage((t + 2) % 3, (t + 2) << 5);
            bf16x8 af[4], bfr[4];
#pragma unroll
            for (int mt = 0; mt < 4; ++mt) af[mt] = *(const bf16x8*)(base + 8192 * 0 + offA[mt]);
#pragma unroll
            for (int nt = 0; nt < 4; ++nt) bfr[nt] = *(const bf16x8*)(base + 8192 + offB[nt]);
#pragma unroll
            for (int mt = 0; mt < 4; ++mt)
#pragma unroll
                for (int nt = 0; nt < 4; ++nt)
                    acc[mt][nt] = __builtin_amdgcn_mfma_f32_16x16x32_bf16(
                        af[mt], bfr[nt], acc[mt][nt], 0, 0, 0);
            if (t < 14)      { WAITV3(); BAR(); }
            else if (t == 14){ WAITV0(); BAR(); }
        }
        // epilogue -> act (L2 out row m at byte 512*m)
#pragma unroll
        for (int nt = 0; nt < 4; ++nt) {
            int col = (wn << 6) + (nt << 4) + lr;
#pragma unroll
            for (int mt = 0; mt < 4; ++mt) {
                int m0 = (wm << 6) + (mt << 4) + crow;
#pragma unroll
                for (int r = 0; r < 4; ++r) {
                    int a = ((m0 + r) << 9) + (col << 1);
                    *(bf16_t*)(act + actswz(a)) = f2bf(tanh_fast(acc[mt][nt][r] + bv[nt]));
                }
            }
        }
        __syncthreads();
    }

    // ================= L3: M=64, A from act (rows at 1024B), out at 1024*m ==
    {
        auto stageB = [&](int s, int kt) {
            char* base = stg + s * 16384;
            GLD16(pb0 + kt, base + (w << 10));
            GLD16(pb1 + kt, base + ((w + 8) << 10));
        };
        f32x4 acc[2][4];
        const f32x4 zero = {0.f, 0.f, 0.f, 0.f};
#pragma unroll
        for (int i = 0; i < 2; ++i)
#pragma unroll
            for (int j = 0; j < 4; ++j) acc[i][j] = zero;

        stageB(0, 0); stageB(1, 32);
        WAITV2(); BAR();
#pragma unroll
        for (int t = 0; t < 16; ++t) {
            const char* base = stg + (t % 3) * 16384;
            if (t + 2 < 16) stageB((t + 2) % 3, (t + 2) << 5);
            bf16x8 af[2], bfr[4];
#pragma unroll
            for (int mt = 0; mt < 2; ++mt) {
                int row = (wm << 5) + (mt << 4) + lr;
                int a = (row << 10) + (t << 6) + (g << 4);
                af[mt] = *(const bf16x8*)(act + actswz(a));
            }
#pragma unroll
            for (int nt = 0; nt < 4; ++nt) bfr[nt] = *(const bf16x8*)(base + offB[nt]);
#pragma unroll
            for (int mt = 0; mt < 2; ++mt)
#pragma unroll
                for (int nt = 0; nt < 4; ++nt)
                    acc[mt][nt] = __builtin_amdgcn_mfma_f32_16x16x32_bf16(
                        af[mt], bfr[nt], acc[mt][nt], 0, 0, 0);
            if (t < 14)      { WAITV2(); BAR(); }
            else if (t == 14){ WAITV0(); BAR(); }
        }
        __syncthreads();   // all reads of act done before in-place writes
#pragma unroll
        for (int nt = 0; nt < 4; ++nt) {
            int col = (wn << 6) + (nt << 4) + lr;
#pragma unroll
            for (int mt = 0; mt < 2; ++mt) {
                int m0 = (wm << 5) + (mt << 4) + crow;
#pragma unroll
                for (int r = 0; r < 4; ++r) {
                    int a = ((m0 + r) << 10) + (col << 1);
                    *(bf16_t*)(act + actswz(a)) = f2bf(tanh_fast(acc[mt][nt][r] + bv[nt]));
                }
            }
        }
        __syncthreads();
    }

    // ================= L4: M=32, A rows chunks {2048j,+1024}, out at 2048*m =
    {
        auto stageB = [&](int s, int kt) {
            char* base = stg + s * 16384;
            GLD16(pb0 + kt, base + (w << 10));
            GLD16(pb1 + kt, base + ((w + 8) << 10));
        };
        f32x4 acc[4];
        const f32x4 zero = {0.f, 0.f, 0.f, 0.f};
#pragma unroll
        for (int j = 0; j < 4; ++j) acc[j] = zero;

        stageB(0, 0); stageB(1, 32);
        WAITV2(); BAR();
#pragma unroll
        for (int t = 0; t < 16; ++t) {
            const char* base = stg + (t % 3) * 16384;
            if (t + 2 < 16) stageB((t + 2) % 3, (t + 2) << 5);
            int row = (wm << 4) + lr;
            int a = (row << 11) + ((t >= 8) ? 1024 : 0) + ((t & 7) << 6) + (g << 4);
            bf16x8 af = *(const bf16x8*)(act + actswz(a));
            bf16x8 bfr[4];
#pragma unroll
            for (int nt = 0; nt < 4; ++nt) bfr[nt] = *(const bf16x8*)(base + offB[nt]);
#pragma unroll
            for (int nt = 0; nt < 4; ++nt)
                acc[nt] = __builtin_amdgcn_mfma_f32_16x16x32_bf16(af, bfr[nt], acc[nt], 0, 0, 0);
            if (t < 14)      { WAITV2(); BAR(); }
            else if (t == 14){ WAITV0(); BAR(); }
        }
        __syncthreads();
#pragma unroll
        for (int nt = 0; nt < 4; ++nt) {
            int col = (wn << 6) + (nt << 4) + lr;
#pragma unroll
            for (int r = 0; r < 4; ++r) {
                int m0 = (wm << 4) + crow + r;
                if (m0 < 32) {
                    int a = (m0 << 11) + (col << 1);
                    *(bf16_t*)(act + actswz(a)) = f2bf(tanh_fast(acc[nt][r] + bv[nt]));
                }
            }
        }
        __syncthreads();
    }

    // ================= L5..L9: M=16 (padded), W in VGPRs, N split 8 waves ===
    {
        bf16x8 wreg[2][16];
#pragma unroll
        for (int nt = 0; nt < 2; ++nt)
#pragma unroll
            for (int kt = 0; kt < 16; ++kt)
                wreg[nt][kt] = *(const bf16x8*)(
                    Wfrag + (size_t)((((2 * w + nt) * 16 + kt) * 64 + lane)) * 8);

#pragma unroll
        for (int lev = 0; lev < 5; ++lev) {
            const int sA = 4096 << lev;         // A row stride (valid rows)
            const int half = sA >> 1;
            f32x4 acc[2];
            const f32x4 zero = {0.f, 0.f, 0.f, 0.f};
            acc[0] = zero; acc[1] = zero;
#pragma unroll
            for (int kt = 0; kt < 16; ++kt) {
                int a = (sA * lr + ((kt >= 8) ? half : 0) + ((kt & 7) << 6) + (g << 4)) & 65535;
                bf16x8 af = *(const bf16x8*)(act + actswz(a));
                acc[0] = __builtin_amdgcn_mfma_f32_16x16x32_bf16(af, wreg[0][kt], acc[0], 0, 0, 0);
                acc[1] = __builtin_amdgcn_mfma_f32_16x16x32_bf16(af, wreg[1][kt], acc[1], 0, 0, 0);
            }
            __syncthreads();                     // all act reads done
            const int valid = 16 >> lev;
#pragma unroll
            for (int nt = 0; nt < 2; ++nt) {
                int col = (w << 5) + (nt << 4) + lr;
#pragma unroll
                for (int r = 0; r < 4; ++r) {
                    int m0 = crow + r;
                    if (m0 < valid) {
                        int a = sA * m0 + (col << 1);
                        *(bf16_t*)(act + actswz(a)) = f2bf(tanh_fast(acc[nt][r] + bvT[nt]));
                    }
                }
            }
            __syncthreads();
        }
    }

    // ================= head: root = act[0..512) (XOR-free region) ==========
    if (tid < 256) {
        const bf16_t* root = (const bf16_t*)act;
        float s = WFb[tid];
#pragma unroll 8
        for (int k = 0; k < 256; ++k)
            s += (float)root[k] * WFwT[k * 256 + tid];
        hid[tid] = fmaxf(s, 0.0f);
    }
    __syncthreads();

    if (w < 5) {
        const float* wo = WOw + w * 256;
        float p = hid[lane] * wo[lane] + hid[lane + 64] * wo[lane + 64] +
                  hid[lane + 128] * wo[lane + 128] + hid[lane + 192] * wo[lane + 192];
#pragma unroll
        for (int off = 32; off > 0; off >>= 1) p += __shfl_down(p, off);
        if (lane == 0) out[(long)blockIdx.x * 5 + w] = p + WOb[w];
    }
}

// ---------------------------------------------------------------------------
extern "C" void kernel_launch(void* const* d_in, const int* in_sizes, int n_in,
                              void* d_out, int out_size, void* d_ws, size_t ws_size,
                              hipStream_t stream) {
    const int*   tokens = (const int*)d_in[0];
    const float* table  = (const float*)d_in[1];
    const float* WRw    = (const float*)d_in[2];
    const float* WRb    = (const float*)d_in[3];
    const float* WFw    = (const float*)d_in[4];
    const float* WFb    = (const float*)d_in[5];
    const float* WOw    = (const float*)d_in[6];
    const float* WOb    = (const float*)d_in[7];
    float* out = (float*)d_out;

    char* ws = (char*)d_ws;
    bf16_t* tableBf = (bf16_t*)ws;                        // 16.4 MB
    bf16_t* Wbf   = (bf16_t*)(ws + (size_t)20971520);     // 256 KB
    bf16_t* Wfrag = (bf16_t*)(ws + (size_t)22020096);     // 256 KB
    float*  WFwT  = (float*)(ws + (size_t)23068672);      // 256 KB
    bf16_t* l1out = (bf16_t*)(ws + (size_t)25165824);     // 33.6 MB

    setup_kernel<<<8256, 256, 0, stream>>>(table, WRw, WFw, tableBf, Wbf, Wfrag, WFwT);
    l1_kernel<<<512, 512, 0, stream>>>(tokens, tableBf, Wbf, WRb, l1out);
    tree_kernel<<<256, 512, 0, stream>>>(l1out, Wbf, Wfrag, WRb, WFwT, WFb, WOw, WOb, out);
}